// Round 9
// baseline (540.604 us; speedup 1.0000x reference)
//
#include <hip/hip_runtime.h>
#include <stdint.h>

// KVCacheAttention: B=4, Sq=2048, Scache=6144, Skv=8192, D=1024, scale=1/8.
// Round 9: 128x128xBK64 4-wave GEMM, 64 KB LDS -> 2 independent blocks/CU
// (TLP fills the vmcnt/barrier stalls that 5 schedule rewrites of the
// 1-block/CU 256^2 kernel could not). K-loop rhythm identical to round 7:
// 2 gll16/phase, vmcnt(2)@ph0, kk1 frags read pre-barrier at ph2, row&7 XOR
// swizzle (0 bank conflicts), setprio around MFMA. Round-7 coalesced
// operand-swapped epilogues (MODE0 QKV routing, MODE1 S^T+exp+rowsum, MODE2 PV).

#define DM 1024
#define NB 4
#define SQN 2048
#define SCC 6144
#define SKV 8192
#define NSPLIT 2
#define KSP (SKV / NSPLIT)

typedef unsigned short u16;
typedef __attribute__((ext_vector_type(8))) short short8;
typedef __attribute__((ext_vector_type(4))) float f32x4;

__device__ __forceinline__ u16 f2bf(float x) {
  unsigned u = __builtin_bit_cast(unsigned, x);
  u += 0x7fffu + ((u >> 16) & 1u);  // RNE; inputs finite
  return (u16)(u >> 16);
}

__device__ __forceinline__ void gll16(const void* g, void* l) {
  __builtin_amdgcn_global_load_lds(
      (const __attribute__((address_space(1))) void*)g,
      (__attribute__((address_space(3))) void*)l, 16, 0, 0);
}

#define FENCE() asm volatile("" ::: "memory")
#define BARRIER()                      \
  do {                                 \
    FENCE();                           \
    __builtin_amdgcn_s_barrier();      \
    FENCE();                           \
  } while (0)

// ---------------- conversions ----------------
__global__ __launch_bounds__(256) void k_cvt(const float* __restrict__ in,
                                             u16* __restrict__ out, long n4) {
  long i = (long)blockIdx.x * 256 + threadIdx.x;
  long st = (long)gridDim.x * 256;
  for (; i < n4; i += st) {
    float4 v = ((const float4*)in)[i];
    ushort4 u;
    u.x = f2bf(v.x); u.y = f2bf(v.y); u.z = f2bf(v.z); u.w = f2bf(v.w);
    ((ushort4*)out)[i] = u;
  }
}

// cached_key [4][6144][1024] f32 -> K bf16 [4][8192][1024] rows 0..6143
__global__ __launch_bounds__(256) void k_cvt_ck(const float* __restrict__ in,
                                                u16* __restrict__ out) {
  const long n4 = (long)NB * SCC * DM / 4;
  long i = (long)blockIdx.x * 256 + threadIdx.x;
  long st = (long)gridDim.x * 256;
  for (; i < n4; i += st) {
    float4 v = ((const float4*)in)[i];
    ushort4 u;
    u.x = f2bf(v.x); u.y = f2bf(v.y); u.z = f2bf(v.z); u.w = f2bf(v.w);
    long e = i * 4;
    int b = (int)(e / ((long)SCC * DM));
    long rem = e - (long)b * SCC * DM;
    *(ushort4*)(out + (long)b * SKV * DM + rem) = u;
  }
}

// ---------------- V^T builder ----------------
__global__ __launch_bounds__(256) void k_build_vt(const float* __restrict__ cv,
                                                  const u16* __restrict__ vtmp,
                                                  u16* __restrict__ VT) {
  __shared__ u16 t[64][65];
  const int kv0 = blockIdx.x * 64;
  const int d0 = blockIdx.y * 64;
  const int b = blockIdx.z;
  const int c = threadIdx.x & 63;
  const int r4 = threadIdx.x >> 6;
#pragma unroll
  for (int p = 0; p < 16; ++p) {
    int kr = p * 4 + r4;
    int kv = kv0 + kr;
    int d = d0 + c;
    u16 u;
    if (kv < SCC)
      u = f2bf(cv[((long)b * SCC + kv) * DM + d]);
    else
      u = vtmp[((long)b * SQN + (kv - SCC)) * DM + d];
    t[kr][c] = u;
  }
  __syncthreads();
#pragma unroll
  for (int p = 0; p < 16; ++p) {
    int dr = p * 4 + r4;
    VT[((long)b * DM + d0 + dr) * SKV + kv0 + c] = t[c][dr];
  }
}

// ---------------- 128x128xBK64 4-wave NT GEMM (2 blocks/CU) ----------------
// 256 thr = 4 waves (2M x 2N); per-wave out 64x64; BK=64 (2 kk-slices).
// LDS 64 KiB: A[2][128][64] @0, B[2][128][64] @32768, XOR-swizzled
// (16B slot ^= row&7) via pre-swizzled global source.
template <int MODE>
__global__ __launch_bounds__(256, 2) void k_gemm4(
    const u16* __restrict__ A, const u16* __restrict__ B0,
    void* __restrict__ C0, void* __restrict__ C1, void* __restrict__ C2,
    float* __restrict__ sums, const float* __restrict__ bias0,
    const float* __restrict__ bias1, const float* __restrict__ bias2) {
  extern __shared__ char smem[];
  const int tid = threadIdx.x;
  const int lane = tid & 63;
  const int wv = tid >> 6;   // 0..3
  const int wr = wv >> 1;    // 0..1
  const int wc = wv & 1;     // 0..1
  const int bm = blockIdx.y * 128;
  const int bn = blockIdx.x * 128;
  const int z = blockIdx.z;

  constexpr int LD = (MODE == 2) ? SKV : DM;
  constexpr int NT = ((MODE == 2) ? KSP : DM) / 64;

  const u16 *Ab_, *Bb_;
  if constexpr (MODE == 0) {
    Ab_ = A + (long)bm * LD;          // W-stack rows: out-d 0..3071
    Bb_ = B0 + (long)bn * LD;         // H tokens
  } else if constexpr (MODE == 1) {
    Ab_ = A + ((long)z * SKV + bm) * LD;   // K rows: kv
    Bb_ = B0 + ((long)z * SQN + bn) * LD;  // Q rows: q
  } else {
    const int bb_ = z / NSPLIT, sp = z % NSPLIT;
    Ab_ = A + ((long)bb_ * SQN + bm) * (long)SKV + (long)sp * KSP;
    Bb_ = B0 + ((long)bb_ * DM + bn) * (long)SKV + (long)sp * KSP;
  }

  // staging: 4 rounds of 32 rows per operand; wave wv covers rows
  // wv*8+(lane>>3) of each round; global col pre-swizzled so the linear LDS
  // write produces the swizzled tile.
  const int srow = wv * 8 + (lane >> 3);
  const int scol = ((lane & 7) ^ (lane >> 3)) * 8;
  const u16* gA = Ab_ + (long)srow * LD + scol;
  const u16* gB = Bb_ + (long)srow * LD + scol;
  u16* lA = (u16*)smem + wv * 512 + lane * 8;            // + buf*8192 + r*2048
  u16* lB = (u16*)(smem + 32768) + wv * 512 + lane * 8;

  // prologue: stage K-tile 0 into buf0
#pragma unroll
  for (int r = 0; r < 4; ++r) gll16(gA + (long)r * 32 * LD, lA + r * 2048);
#pragma unroll
  for (int r = 0; r < 4; ++r) gll16(gB + (long)r * 32 * LD, lB + r * 2048);

  f32x4 acc[4][4];
#pragma unroll
  for (int m = 0; m < 4; ++m)
#pragma unroll
    for (int n = 0; n < 4; ++n)
#pragma unroll
      for (int j = 0; j < 4; ++j) acc[m][n][j] = 0.0f;

  const int alane = lane & 15;
  const int sw = lane & 7;   // row&7 == lane&7 for all frag rows
  const int s0 = lane >> 4;  // base 16B slot

#define AFRAG(M, KK)                                                  \
  (*(const short8*)(As + (wr * 64 + (M)*16 + alane) * 128 +           \
                    (((s0 + 4 * (KK)) ^ sw) * 16)))
#define BFRAG(N, KK)                                                  \
  (*(const short8*)(Bs + (wc * 64 + (N)*16 + alane) * 128 +           \
                    (((s0 + 4 * (KK)) ^ sw) * 16)))
#define MFMA8(N0, N1)                                                       \
  __builtin_amdgcn_s_setprio(1);                                            \
  _Pragma("unroll") for (int m = 0; m < 4; ++m) {                           \
    acc[m][N0] = __builtin_amdgcn_mfma_f32_16x16x32_bf16(aF[m], bF[N0],     \
                                                         acc[m][N0], 0, 0, 0); \
    acc[m][N1] = __builtin_amdgcn_mfma_f32_16x16x32_bf16(aF[m], bF[N1],     \
                                                         acc[m][N1], 0, 0, 0); \
  }                                                                         \
  __builtin_amdgcn_s_setprio(0);

  short8 aF[4], bF[4];

  for (int kt = 0; kt < NT; ++kt) {
    const int b = kt & 1;
    const char* As = smem + b * 16384;
    const char* Bs = smem + 32768 + b * 16384;
    const int d = (b ^ 1) * 8192;
    const long knext = (long)((kt + 1 < NT) ? kt + 1 : kt) * 64;
    const u16* gAn = gA + knext;
    const u16* gBn = gB + knext;

    // ---- phase 0: stage A r0,r1; vmcnt(2); bar; read kk0; MFMA n0,n1 ----
    gll16(gAn, lA + d);
    gll16(gAn + (long)32 * LD, lA + d + 2048);
    asm volatile("s_waitcnt vmcnt(2)" ::: "memory");
    BARRIER();
#pragma unroll
    for (int m = 0; m < 4; ++m) aF[m] = AFRAG(m, 0);
#pragma unroll
    for (int n = 0; n < 4; ++n) bF[n] = BFRAG(n, 0);
    MFMA8(0, 1);
    BARRIER();

    // ---- phase 1: stage A r2,r3; bar; MFMA n2,n3 (kk0) ----
    gll16(gAn + (long)64 * LD, lA + d + 2 * 2048);
    gll16(gAn + (long)96 * LD, lA + d + 3 * 2048);
    BARRIER();
    MFMA8(2, 3);
    BARRIER();

    // ---- phase 2: read kk1 (pre-barrier); stage B r0,r1; bar; MFMA ----
#pragma unroll
    for (int m = 0; m < 4; ++m) aF[m] = AFRAG(m, 1);
#pragma unroll
    for (int n = 0; n < 4; ++n) bF[n] = BFRAG(n, 1);
    gll16(gBn, lB + d);
    gll16(gBn + (long)32 * LD, lB + d + 2048);
    BARRIER();
    MFMA8(0, 1);
    BARRIER();

    // ---- phase 3: stage B r2,r3; bar; MFMA n2,n3 (kk1) ----
    gll16(gBn + (long)64 * LD, lB + d + 2 * 2048);
    gll16(gBn + (long)96 * LD, lB + d + 3 * 2048);
    BARRIER();
    MFMA8(2, 3);
    BARRIER();
  }
#undef AFRAG
#undef BFRAG
#undef MFMA8

  // ---------------- epilogue (j-dim contiguous in output) ----------------
  const int rsub = (lane >> 4) * 4;

  if constexpr (MODE == 0) {
    // acc row = out-d, col = token. which = bm>>10 uniform per block.
    const int which = bm >> 10;
    const float* bp = which == 0 ? bias0 : (which == 1 ? bias1 : bias2);
    u16* Cq = (u16*)C0;
    u16* Ck = (u16*)C1;
    u16* Cv = (u16*)C2;
    const int od_base = (bm & 1023) + wr * 64 + rsub;
#pragma unroll
    for (int n = 0; n < 4; ++n) {
      int token = bn + wc * 64 + n * 16 + alane;
      u16* dst;
      if (which == 1) {
        int b = token >> 11, ss = token & 2047;
        dst = Ck + ((long)b * SKV + SCC + ss) * DM;
      } else if (which == 0) {
        dst = Cq + (long)token * DM;
      } else {
        dst = Cv + (long)token * DM;
      }
#pragma unroll
      for (int m = 0; m < 4; ++m) {
        int cc = od_base + m * 16;
        float4 bb = *(const float4*)(bp + cc);
        ushort4 u;
        u.x = f2bf(acc[m][n][0] + bb.x);
        u.y = f2bf(acc[m][n][1] + bb.y);
        u.z = f2bf(acc[m][n][2] + bb.z);
        u.w = f2bf(acc[m][n][3] + bb.w);
        *(ushort4*)(dst + cc) = u;
      }
    }
  } else if constexpr (MODE == 1) {
    // acc row = kv, col = q. store P[q][kv] ushort4; rowsum per q.
    u16* Pp = (u16*)C0 + (long)z * SQN * SKV;
    float* sb = sums + z * SQN;
    const float CE = 0.18033688011112042f;  // log2(e)/8
    const int kv_base = bm + wr * 64 + rsub;
#pragma unroll
    for (int n = 0; n < 4; ++n) {
      int q = bn + wc * 64 + n * 16 + alane;
      u16* prow = Pp + (long)q * SKV;
      float part = 0.f;
#pragma unroll
      for (int m = 0; m < 4; ++m) {
        int kv = kv_base + m * 16;
        float e0 = exp2f(acc[m][n][0] * CE);
        float e1 = exp2f(acc[m][n][1] * CE);
        float e2 = exp2f(acc[m][n][2] * CE);
        float e3 = exp2f(acc[m][n][3] * CE);
        part += (e0 + e1) + (e2 + e3);
        ushort4 u;
        u.x = f2bf(e0); u.y = f2bf(e1); u.z = f2bf(e2); u.w = f2bf(e3);
        *(ushort4*)(prow + kv) = u;
      }
      part += __shfl_xor(part, 16);
      part += __shfl_xor(part, 32);
      if ((lane >> 4) == 0) atomicAdd(&sb[q], part);
    }
  } else {
    // acc row = q, col = d. f32 stores, 64B segments per 16 lanes.
    float* Cp = (float*)C0 + (long)z * SQN * DM;
#pragma unroll
    for (int n = 0; n < 4; ++n) {
      int col = bn + wc * 64 + n * 16 + alane;
#pragma unroll
      for (int m = 0; m < 4; ++m)
#pragma unroll
        for (int j = 0; j < 4; ++j) {
          int row = bm + wr * 64 + m * 16 + rsub + j;
          Cp[(long)row * DM + col] = acc[m][n][j];
        }
    }
  }
}

// ---------------- reduce split-K partials + normalize ----------------
__global__ __launch_bounds__(256) void k_reduce(const float* __restrict__ Op,
                                                const float* __restrict__ sums,
                                                float* __restrict__ out) {
  const long n4 = (long)NB * SQN * DM / 4;
  long i = (long)blockIdx.x * 256 + threadIdx.x;
  if (i >= n4) return;
  long e = i * 4;
  int b = (int)(e / ((long)SQN * DM));
  long rem = e - (long)b * SQN * DM;
  int row = (int)(rem / DM);
  const long z4 = (long)SQN * DM / 4;
  long i0 = (long)(b * NSPLIT) * z4 + (rem >> 2);
  float4 a0 = ((const float4*)Op)[i0];
  float4 a1 = ((const float4*)Op)[i0 + z4];
  float inv = 1.0f / sums[b * SQN + row];
  float4 r;
  r.x = (a0.x + a1.x) * inv;
  r.y = (a0.y + a1.y) * inv;
  r.z = (a0.z + a1.z) * inv;
  r.w = (a0.w + a1.w) * inv;
  ((float4*)out)[i] = r;
}

// ---------------- launch ----------------
extern "C" void kernel_launch(void* const* d_in, const int* in_sizes, int n_in,
                              void* d_out, int out_size, void* d_ws, size_t ws_size,
                              hipStream_t stream) {
  const float* hidden = (const float*)d_in[0];
  const float* ck = (const float*)d_in[1];
  const float* cv = (const float*)d_in[2];
  const float* Wq = (const float*)d_in[3];
  const float* bq = (const float*)d_in[4];
  const float* Wk = (const float*)d_in[5];
  const float* bk = (const float*)d_in[6];
  const float* Wv = (const float*)d_in[7];
  const float* bv = (const float*)d_in[8];
  (void)in_sizes; (void)n_in; (void)out_size; (void)ws_size;

  hipFuncSetAttribute(reinterpret_cast<const void*>(&k_gemm4<0>),
                      hipFuncAttributeMaxDynamicSharedMemorySize, 65536);
  hipFuncSetAttribute(reinterpret_cast<const void*>(&k_gemm4<1>),
                      hipFuncAttributeMaxDynamicSharedMemorySize, 65536);
  hipFuncSetAttribute(reinterpret_cast<const void*>(&k_gemm4<2>),
                      hipFuncAttributeMaxDynamicSharedMemorySize, 65536);

  char* base = (char*)d_ws;
  size_t off = 0;
  auto alloc = [&](size_t bytes) {
    char* p = base + off;
    off = (off + bytes + 255) & ~(size_t)255;
    return p;
  };
  // region0 (dead before PV): Hb, weights, Qb, Kb, Vtmp. Opart aliases it.
  u16* Hb = (u16*)alloc((size_t)NB * SQN * DM * 2);
  u16* Wall = (u16*)alloc((size_t)3 * DM * DM * 2);  // Wq|Wk|Wv stacked
  u16* Qb = (u16*)alloc((size_t)NB * SQN * DM * 2);
  u16* Kb = (u16*)alloc((size_t)NB * SKV * DM * 2);
  u16* Vtmp = (u16*)alloc((size_t)NB * SQN * DM * 2);
  float* Opart = (float*)base;  // [NB*NSPLIT][2048][1024] f32, aliases region0
  size_t opart_bytes = (size_t)NB * NSPLIT * SQN * DM * 4;
  if (off < opart_bytes) off = (opart_bytes + 255) & ~(size_t)255;
  u16* VT = (u16*)alloc((size_t)NB * DM * SKV * 2);
  u16* P = (u16*)alloc((size_t)NB * SQN * SKV * 2);
  float* sums = (float*)alloc((size_t)NB * SQN * 4);

  // conversions
  k_cvt<<<2048, 256, 0, stream>>>(hidden, Hb, (long)NB * SQN * DM / 4);
  k_cvt<<<512, 256, 0, stream>>>(Wq, Wall, (long)DM * DM / 4);
  k_cvt<<<512, 256, 0, stream>>>(Wk, Wall + (size_t)DM * DM, (long)DM * DM / 4);
  k_cvt<<<512, 256, 0, stream>>>(Wv, Wall + (size_t)2 * DM * DM, (long)DM * DM / 4);
  k_cvt_ck<<<4096, 256, 0, stream>>>(ck, Kb);

  // fused QKV projection: A=W-stack [3072][1024], B=H [8192][1024]
  k_gemm4<0><<<dim3(64, 24, 1), 256, 65536, stream>>>(
      Wall, Hb, Qb, Kb, Vtmp, nullptr, bq, bk, bv);

  // V^T
  k_build_vt<<<dim3(SKV / 64, DM / 64, NB), 256, 0, stream>>>(cv, Vtmp, VT);

  // S^T = K.Q^T with fused exp + row sums (batched over 4): A=K, B=Q
  hipMemsetAsync(sums, 0, (size_t)NB * SQN * 4, stream);
  k_gemm4<1><<<dim3(SQN / 128, SKV / 128, NB), 256, 65536, stream>>>(
      Kb, Qb, P, nullptr, nullptr, sums, nullptr, nullptr, nullptr);

  // PV split-K(2): z = b*NSPLIT + split
  k_gemm4<2><<<dim3(DM / 128, SQN / 128, NB * NSPLIT), 256, 65536, stream>>>(
      P, VT, Opart, nullptr, nullptr, nullptr, nullptr, nullptr, nullptr);

  // reduce partials + normalize
  k_reduce<<<(NB * SQN * DM / 4 + 255) / 256, 256, 0, stream>>>(
      Opart, sums, (float*)d_out);
}